// Round 1
// baseline (481.454 us; speedup 1.0000x reference)
//
#include <hip/hip_runtime.h>
#include <math.h>

// Problem constants (match reference)
#define BB 1024
#define TT 2048
#define II 2
#define HH 64

// One wave (64 lanes) per batch element. lane = hidden unit j.
// h_t = relu(h_{t-1} @ Wh^T + x_t @ Wx^T);  out[b] = ||h_T||_2
__global__ __launch_bounds__(64, 1) void rnn_scan_kernel(
    const float* __restrict__ x,    // [B, T, 2]
    const float* __restrict__ Wh,   // [64, 64] row-major, row = out feature
    const float* __restrict__ Wx,   // [64, 2]
    float* __restrict__ out)        // [B]
{
    const int b = blockIdx.x;
    const int j = threadIdx.x;   // 0..63 (lane == hidden index)

    // Preload row j of Wh into 64 VGPRs (reused T times).
    float w[HH];
#pragma unroll
    for (int k4 = 0; k4 < HH / 4; ++k4) {
        const float4 v = *reinterpret_cast<const float4*>(&Wh[(size_t)j * HH + k4 * 4]);
        w[k4 * 4 + 0] = v.x;
        w[k4 * 4 + 1] = v.y;
        w[k4 * 4 + 2] = v.z;
        w[k4 * 4 + 3] = v.w;
    }
    const float wx0 = Wx[j * 2 + 0];
    const float wx1 = Wx[j * 2 + 1];

    const float* __restrict__ xb = x + (size_t)b * TT * II;

    float h = 0.0f;

#pragma unroll 2
    for (int t = 0; t < TT; ++t) {
        // x_t is wave-uniform (same for all lanes) -> scalar loads,
        // independent of the recurrence so they pipeline ahead.
        const float x0 = xb[t * 2 + 0];
        const float x1 = xb[t * 2 + 1];

        // acc init = x_t @ Wx^T (per-lane row of Wx)
        float acc0 = fmaf(x1, wx1, x0 * wx0);
        float acc1 = 0.0f, acc2 = 0.0f, acc3 = 0.0f;

        const int hbits = __float_as_int(h);
        // h_new[j] = sum_k h[k] * Wh[j][k]
        // broadcast h[k] via v_readlane -> SGPR, fmac with SGPR operand.
#pragma unroll
        for (int k = 0; k < HH; k += 4) {
            acc0 = fmaf(__int_as_float(__builtin_amdgcn_readlane(hbits, k + 0)), w[k + 0], acc0);
            acc1 = fmaf(__int_as_float(__builtin_amdgcn_readlane(hbits, k + 1)), w[k + 1], acc1);
            acc2 = fmaf(__int_as_float(__builtin_amdgcn_readlane(hbits, k + 2)), w[k + 2], acc2);
            acc3 = fmaf(__int_as_float(__builtin_amdgcn_readlane(hbits, k + 3)), w[k + 3], acc3);
        }
        h = fmaxf((acc0 + acc1) + (acc2 + acc3), 0.0f);
    }

    // ||h_T||_2 across the wave
    float s = h * h;
#pragma unroll
    for (int off = 32; off > 0; off >>= 1)
        s += __shfl_xor(s, off, 64);
    if (j == 0)
        out[b] = sqrtf(s);
}

extern "C" void kernel_launch(void* const* d_in, const int* in_sizes, int n_in,
                              void* d_out, int out_size, void* d_ws, size_t ws_size,
                              hipStream_t stream) {
    const float* x  = (const float*)d_in[0];   // [B,T,2]
    const float* Wh = (const float*)d_in[1];   // [64,64]
    const float* Wx = (const float*)d_in[2];   // [64,2]
    float* out = (float*)d_out;                // [B]

    rnn_scan_kernel<<<dim3(BB), dim3(64), 0, stream>>>(x, Wh, Wx, out);
}